// Round 6
// baseline (85.799 us; speedup 1.0000x reference)
//
#include <hip/hip_runtime.h>
#include <hip/hip_bf16.h>

#define FEATN 501
#define KPAD 1024
#define MSTRIDE 1032   // Ml row stride (ushorts): 2064 B -> 2-way (free) b128 conflicts
#define NB 8192
#define NT 512
#define DTC 0.01f

typedef __attribute__((ext_vector_type(8))) short short8;
typedef __attribute__((ext_vector_type(4))) short short4v;
typedef __attribute__((ext_vector_type(4))) float f32x4;

__device__ __forceinline__ float softplus_f(float x) {
    return fmaxf(x, 0.f) + log1pf(expf(-fabsf(x)));
}
__device__ __forceinline__ ushort f2bf(float x) {
    __hip_bfloat16 h = __float2bfloat16(x);   // RNE
    return *reinterpret_cast<ushort*>(&h);
}
__device__ __forceinline__ void gl_lds16(const void* g, void* l) {
    __builtin_amdgcn_global_load_lds(
        (const __attribute__((address_space(1))) void*)g,
        (__attribute__((address_space(3))) void*)l, 16, 0, 0);
}
// one DPP-add reduction step (pure VALU, no DS)
__device__ __forceinline__ float dpp_add(float x, const int ctrl) {
    int s = __builtin_bit_cast(int, x);
    int y;
    switch (ctrl) {   // ctrl must be a literal constant per call site
    case 0xB1:  y = __builtin_amdgcn_update_dpp(0, s, 0xB1, 0xf, 0xf, true); break;
    case 0x4E:  y = __builtin_amdgcn_update_dpp(0, s, 0x4E, 0xf, 0xf, true); break;
    default:    y = __builtin_amdgcn_update_dpp(0, s, 0x141, 0xf, 0xf, true); break;
    }
    return x + __builtin_bit_cast(float, y);
}

// ---------------- wtrans: W[1002][64]x2 -> Wt[128][1024] bf16 --------------
// k-map: k' in [0,501) -> W row k' (E part); k' in [512,1013) -> W row k'-11
// (nu part); else 0. Matches enc's Ml layout (8B-aligned LDS writes).
__global__ __launch_bounds__(256) void wtrans_kernel(
    const float* __restrict__ Bw1, const float* __restrict__ bw1,
    ushort* __restrict__ Wt) {
    const int h = blockIdx.x;
    const int lane = threadIdx.x & 63;
    const int wv = threadIdx.x >> 6;
    const float* W = (h < 64) ? Bw1 : bw1;
    const int col = h & 63;
    #pragma unroll
    for (int it = 0; it < 4; ++it) {
        const int k = it * 256 + wv * 64 + lane;
        const int ksrc = (k < FEATN) ? k
                       : (k >= 512 && k < 512 + FEATN) ? k - 11 : -1;
        const float v = (ksrc >= 0) ? W[(size_t)ksrc * 64 + col] : 0.f;
        Wt[(size_t)h * KPAD + k] = f2bf(v);
    }
}

// ---------------- enc (fused prep + GEMM): coefs for 16 batches ------------
// grid 512 x 256. Phase A: read E/nu, harmonic stats, bf16 -> static Ml LDS.
// K-loop: W-frags as global b128 (L2-resident Wt), B-frags from Ml, NO
// barriers -> compiler pipelines loads across steps.
__global__ __launch_bounds__(256) void enc_kernel(
    const float* __restrict__ E, const float* __restrict__ nu,
    const ushort* __restrict__ Wt,
    const float* __restrict__ Bb1, const float* __restrict__ bb1,
    const float* __restrict__ Bw2, const float* __restrict__ Bb2,
    const float* __restrict__ bw2, const float* __restrict__ bb2,
    float* __restrict__ xi) {
    __shared__ ushort Ml[16 * MSTRIDE];   // [b][k'] bf16, ~33 KB, static
    __shared__ float hid[128][17];
    __shared__ float nups[16], Eps[16];

    const int tid = threadIdx.x;
    const int wv = tid >> 6, lane = tid & 63;
    const int bb0 = blockIdx.x * 16;

    // ---- phase A: 16 threads per batch ----
    {
        const int bl = tid >> 4;          // 0..15
        const int t16 = tid & 15;
        const size_t base = (size_t)(bb0 + bl) * FEATN;
        float s1 = 0.f, s2 = 0.f;
        #pragma unroll
        for (int it = 0; it < 8; ++it) {
            const int i0 = it * 64 + t16 * 4;
            if (i0 + 3 < FEATN) {
                const float4 Ev = *(const float4*)(E + base + i0);
                const float4 nv = *(const float4*)(nu + base + i0);
                const float i0v = 1.0f / nv.x, i1v = 1.0f / nv.y;
                const float i2v = 1.0f / nv.z, i3v = 1.0f / nv.w;
                s1 += (i0v + i1v) + (i2v + i3v);
                s2 = fmaf(Ev.x, i0v * i0v, s2);
                s2 = fmaf(Ev.y, i1v * i1v, s2);
                s2 = fmaf(Ev.z, i2v * i2v, s2);
                s2 = fmaf(Ev.w, i3v * i3v, s2);
                short4v ep = {(short)f2bf(Ev.x), (short)f2bf(Ev.y),
                              (short)f2bf(Ev.z), (short)f2bf(Ev.w)};
                short4v np_ = {(short)f2bf(nv.x), (short)f2bf(nv.y),
                               (short)f2bf(nv.z), (short)f2bf(nv.w)};
                *(short4v*)&Ml[bl * MSTRIDE + i0] = ep;
                *(short4v*)&Ml[bl * MSTRIDE + 512 + i0] = np_;
            } else if (i0 < FEATN) {      // i0 == 500
                const float Ev = E[base + i0];
                const float nv = nu[base + i0];
                const float iv = 1.0f / nv;
                s1 += iv;
                s2 = fmaf(Ev, iv * iv, s2);
                Ml[bl * MSTRIDE + i0] = f2bf(Ev);
                Ml[bl * MSTRIDE + 512 + i0] = f2bf(nv);
            }
        }
        if (t16 < 11) {                   // zero pads 501..511, 1013..1023
            Ml[bl * MSTRIDE + FEATN + t16] = 0;
            Ml[bl * MSTRIDE + 512 + FEATN + t16] = 0;
        }
        #pragma unroll
        for (int o = 1; o < 16; o <<= 1) {
            s1 += __shfl_xor(s1, o);
            s2 += __shfl_xor(s2, o);
        }
        if (t16 == 0) {
            const float np = (float)FEATN / s1;
            nups[bl] = np;
            Eps[bl] = (s2 / (float)FEATN) * np * np;
        }
    }
    __syncthreads();

    // ---- K loop: no barriers, W from L2, B from static LDS ----
    const int r15 = lane & 15, kg = lane >> 4;
    const ushort* wp0 = Wt + (size_t)(wv * 32 + r15) * KPAD + kg * 8;
    const ushort* wp1 = wp0 + 16 * KPAD;
    const int boff = r15 * MSTRIDE + kg * 8;

    f32x4 acc0 = {0.f, 0.f, 0.f, 0.f}, acc1 = acc0;
    #pragma unroll 4
    for (int s = 0; s < 32; ++s) {
        const int kb = s * 32;
        const short8 a0 = *(const short8*)(wp0 + kb);
        const short8 a1 = *(const short8*)(wp1 + kb);
        const short8 b = *(const short8*)&Ml[boff + kb];
        acc0 = __builtin_amdgcn_mfma_f32_16x16x32_bf16(a0, b, acc0, 0, 0, 0);
        acc1 = __builtin_amdgcn_mfma_f32_16x16x32_bf16(a1, b, acc1, 0, 0, 0);
    }

    // ---- bias + activation -> hid ----
    #pragma unroll
    for (int t = 0; t < 2; ++t) {
        #pragma unroll
        for (int r = 0; r < 4; ++r) {
            const int h = wv * 32 + t * 16 + kg * 4 + r;
            const float bias = (h < 64) ? Bb1[h] : bb1[h - 64];
            float v = (t ? acc1[r] : acc0[r]) + bias;
            v = (h < 64) ? fmaxf(v, 0.f) : softplus_f(v);
            hid[h][r15] = v;
        }
    }
    __syncthreads();

    // ---- layer 2 + coefficient write ----
    if (tid < 128) {
        const int bl = tid >> 3, k = tid & 7;
        float dB = 0.f, db = 0.f;
        #pragma unroll 8
        for (int h = 0; h < 64; ++h) {
            dB = fmaf(hid[h][bl], Bw2[h * 8 + k], dB);
            db = fmaf(hid[64 + h][bl], bw2[h * 8 + k], db);
        }
        const float Bm = dB + Bb2[k];
        const float be = softplus_f(db + bb2[k]);
        float Bs = Bm;
        Bs += __shfl_xor(Bs, 1);
        Bs += __shfl_xor(Bs, 2);
        Bs += __shfl_xor(Bs, 4);
        float* cb = xi + (size_t)(bb0 + bl) * 4096;
        cb[k] = 1.f - DTC * be * (Bm + Bs);
        cb[8 + k] = DTC * be * Bm;
        cb[16 + k] = Bm;
        if (k == 0) { cb[24] = Bs * Eps[bl]; cb[25] = nups[bl]; }
    }
}

// ---------------- time loop: LDS-staged inputs, store-only main loop -------
// grid 2048 x 256: one wave per batch. lane = j*8+k.
__global__ __launch_bounds__(256) void time_kernel(
    const float* __restrict__ e, const float* __restrict__ ed,
    const float* coef, float* stress, float* xi_out) {
    __shared__ float els[4][512];
    __shared__ float pls[4][512];
    const int wv = threadIdx.x >> 6;
    const int wid = (blockIdx.x << 2) + wv;
    const int lane = threadIdx.x & 63;
    const int j = lane >> 3, k = lane & 7;

    const float* eb = e + (size_t)wid * NT;
    const float* edb = ed + (size_t)wid * NT;
    // stage this wave's entire input (wave-local: no barrier needed)
    gl_lds16(eb + lane * 4, &els[wv][0]);
    gl_lds16(eb + 256 + lane * 4, &els[wv][256]);
    gl_lds16(edb + lane * 4, &pls[wv][0]);
    gl_lds16(edb + 256 + lane * 4, &pls[wv][256]);

    const float* cb = coef + (size_t)wid * 4096;
    const float a = cb[k];
    const float c = cb[8 + k];
    const float Bm = cb[16 + k];
    const float sE = cb[24];
    const float nup = cb[25];
    // coef loads + LDS staging must land before LDS reads / aliased stores
    asm volatile("s_waitcnt vmcnt(0)" ::: "memory");

    // per-lane window constants: xi(t0+j) = a^j xi(t0) + sum_{i<j} a^(j-1-i) c u_i
    const float a2 = a * a, a4 = a2 * a2;
    const float P = a4 * a4;                 // a^8
    float A = 1.f;                           // a^j
    if (j & 1) A *= a;
    if (j & 2) A *= a2;
    if (j & 4) A *= a4;
    float pw[8];                             // pw[i] = (i<j) ? a^(j-1-i)*c : 0
    {
        float run = c;
        #pragma unroll
        for (int i = 7; i >= 0; --i) {
            const bool on = (i < j);
            pw[i] = on ? run : 0.f;
            run = on ? run * a : run;
        }
    }
    float pv[8];                             // pv[i] = a^(7-i)*c
    pv[7] = c;
    #pragma unroll
    for (int i = 6; i >= 0; --i) pv[i] = a * pv[i + 1];

    float* xb = xi_out + (size_t)wid * (NT * 8);
    float* sb = stress + (size_t)wid * NT;
    const float* el = &els[wv][0];
    const float* pl = &pls[wv][0];

    // register-pipelined window reads from LDS
    float4 q0 = *(const float4*)(el);
    float4 q1 = *(const float4*)(el + 4);
    float uj = el[j];
    float pj = pl[j];

    float xs = 0.f;
    #pragma unroll 2
    for (int t0 = 0; t0 < NT; t0 += 8) {
        const float u0 = q0.x, u1 = q0.y, u2 = q0.z, u3 = q0.w;
        const float u4 = q1.x, u5 = q1.y, u6 = q1.z, u7 = q1.w;
        const float cuj = uj, cpj = pj;
        if (t0 + 8 < NT) {                   // prefetch next window (LDS)
            q0 = *(const float4*)(el + t0 + 8);
            q1 = *(const float4*)(el + t0 + 12);
            uj = el[t0 + 8 + j];
            pj = pl[t0 + 8 + j];
        }
        float xi_j = A * xs;
        xi_j = fmaf(pw[0], u0, xi_j);
        xi_j = fmaf(pw[1], u1, xi_j);
        xi_j = fmaf(pw[2], u2, xi_j);
        xi_j = fmaf(pw[3], u3, xi_j);
        xi_j = fmaf(pw[4], u4, xi_j);
        xi_j = fmaf(pw[5], u5, xi_j);
        xi_j = fmaf(pw[6], u6, xi_j);
        xi_j = fmaf(pw[7], u7, xi_j);
        float ns = P * xs;
        ns = fmaf(pv[0], u0, ns);
        ns = fmaf(pv[1], u1, ns);
        ns = fmaf(pv[2], u2, ns);
        ns = fmaf(pv[3], u3, ns);
        ns = fmaf(pv[4], u4, ns);
        ns = fmaf(pv[5], u5, ns);
        ns = fmaf(pv[6], u6, ns);
        ns = fmaf(pv[7], u7, ns);
        xs = ns;
        __builtin_nontemporal_store(xi_j, &xb[t0 * 8 + lane]);   // 256B/wave
        float r = Bm * (cuj - xi_j);
        r = dpp_add(r, 0xB1);                // + lane^1
        r = dpp_add(r, 0x4E);                // + lane^2
        r = dpp_add(r, 0x141);               // + other quad (within 8)
        if (k == 0)
            __builtin_nontemporal_store(fmaf(sE, cuj, fmaf(nup, cpj, r)),
                                        &sb[t0 + j]);
    }
}

extern "C" void kernel_launch(void* const* d_in, const int* in_sizes, int n_in,
                              void* d_out, int out_size, void* d_ws, size_t ws_size,
                              hipStream_t stream) {
    const float* e   = (const float*)d_in[0];
    const float* ed  = (const float*)d_in[1];
    const float* E   = (const float*)d_in[2];
    const float* nu  = (const float*)d_in[3];
    const float* Bw1 = (const float*)d_in[4];
    const float* Bb1 = (const float*)d_in[5];
    const float* Bw2 = (const float*)d_in[6];
    const float* Bb2 = (const float*)d_in[7];
    const float* bw1 = (const float*)d_in[8];
    const float* bb1 = (const float*)d_in[9];
    const float* bw2 = (const float*)d_in[10];
    const float* bb2 = (const float*)d_in[11];

    float* out = (float*)d_out;
    float* stress = out;                        // [B*T] floats
    float* xi = out + (size_t)NB * NT;          // [B*T*8] floats
    ushort* Wt = (ushort*)out;                  // 256 KB stash in stress region

    wtrans_kernel<<<128, 256, 0, stream>>>(Bw1, bw1, Wt);
    enc_kernel<<<512, 256, 0, stream>>>(E, nu, Wt, Bb1, bb1,
                                        Bw2, Bb2, bw2, bb2, xi);
    time_kernel<<<2048, 256, 0, stream>>>(e, ed, xi, stress, xi);
}

// Round 7
// 68.811 us; speedup vs baseline: 1.2469x; 1.2469x over previous
//
#include <hip/hip_runtime.h>
#include <hip/hip_bf16.h>

#define FEATN 501
#define KPAD 1024
#define MSTRIDE 1032   // Ml row stride (ushorts): 2064 B -> 2-way (free) b128 conflicts
#define NB 8192
#define NT 512
#define DTC 0.01f

typedef __attribute__((ext_vector_type(8))) short short8;
typedef __attribute__((ext_vector_type(4))) short short4v;
typedef __attribute__((ext_vector_type(4))) float f32x4;

__device__ __forceinline__ float softplus_f(float x) {
    return fmaxf(x, 0.f) + log1pf(expf(-fabsf(x)));
}
__device__ __forceinline__ ushort f2bf(float x) {
    __hip_bfloat16 h = __float2bfloat16(x);   // RNE
    return *reinterpret_cast<ushort*>(&h);
}
__device__ __forceinline__ void gl_lds16(const void* g, void* l) {
    __builtin_amdgcn_global_load_lds(
        (const __attribute__((address_space(1))) void*)g,
        (__attribute__((address_space(3))) void*)l, 16, 0, 0);
}
// one DPP-add reduction step (pure VALU, no DS)
__device__ __forceinline__ float dpp_add(float x, const int ctrl) {
    int s = __builtin_bit_cast(int, x);
    int y;
    switch (ctrl) {   // ctrl must be a literal constant per call site
    case 0xB1:  y = __builtin_amdgcn_update_dpp(0, s, 0xB1, 0xf, 0xf, true); break;
    case 0x4E:  y = __builtin_amdgcn_update_dpp(0, s, 0x4E, 0xf, 0xf, true); break;
    default:    y = __builtin_amdgcn_update_dpp(0, s, 0x141, 0xf, 0xf, true); break;
    }
    return x + __builtin_bit_cast(float, y);
}

// ---------------- wtrans: W[1002][64]x2 -> Wt[128][1024] bf16 --------------
// k-map: k' in [0,501) -> W row k' (E part); k' in [512,1013) -> W row k'-11
// (nu part); else 0. Matches enc's Ml layout (8B-aligned LDS writes).
__global__ __launch_bounds__(256) void wtrans_kernel(
    const float* __restrict__ Bw1, const float* __restrict__ bw1,
    ushort* __restrict__ Wt) {
    const int h = blockIdx.x;
    const int lane = threadIdx.x & 63;
    const int wv = threadIdx.x >> 6;
    const float* W = (h < 64) ? Bw1 : bw1;
    const int col = h & 63;
    #pragma unroll
    for (int it = 0; it < 4; ++it) {
        const int k = it * 256 + wv * 64 + lane;
        const int ksrc = (k < FEATN) ? k
                       : (k >= 512 && k < 512 + FEATN) ? k - 11 : -1;
        const float v = (ksrc >= 0) ? W[(size_t)ksrc * 64 + col] : 0.f;
        Wt[(size_t)h * KPAD + k] = f2bf(v);
    }
}

// ---------------- enc (fused prep + GEMM): coefs for 16 batches ------------
// grid 512 x 256. Phase A: read E/nu, harmonic stats, bf16 -> static Ml LDS.
// K-loop: W-frags as global b128 (L2-resident Wt), B-frags from Ml, NO
// barriers -> compiler pipelines loads across steps.
__global__ __launch_bounds__(256) void enc_kernel(
    const float* __restrict__ E, const float* __restrict__ nu,
    const ushort* __restrict__ Wt,
    const float* __restrict__ Bb1, const float* __restrict__ bb1,
    const float* __restrict__ Bw2, const float* __restrict__ Bb2,
    const float* __restrict__ bw2, const float* __restrict__ bb2,
    float* __restrict__ xi) {
    __shared__ ushort Ml[16 * MSTRIDE];   // [b][k'] bf16, ~33 KB, static
    __shared__ float hid[128][17];
    __shared__ float nups[16], Eps[16];

    const int tid = threadIdx.x;
    const int wv = tid >> 6, lane = tid & 63;
    const int bb0 = blockIdx.x * 16;

    // ---- phase A: 16 threads per batch ----
    {
        const int bl = tid >> 4;          // 0..15
        const int t16 = tid & 15;
        const size_t base = (size_t)(bb0 + bl) * FEATN;
        float s1 = 0.f, s2 = 0.f;
        #pragma unroll
        for (int it = 0; it < 8; ++it) {
            const int i0 = it * 64 + t16 * 4;
            if (i0 + 3 < FEATN) {
                const float4 Ev = *(const float4*)(E + base + i0);
                const float4 nv = *(const float4*)(nu + base + i0);
                const float i0v = 1.0f / nv.x, i1v = 1.0f / nv.y;
                const float i2v = 1.0f / nv.z, i3v = 1.0f / nv.w;
                s1 += (i0v + i1v) + (i2v + i3v);
                s2 = fmaf(Ev.x, i0v * i0v, s2);
                s2 = fmaf(Ev.y, i1v * i1v, s2);
                s2 = fmaf(Ev.z, i2v * i2v, s2);
                s2 = fmaf(Ev.w, i3v * i3v, s2);
                short4v ep = {(short)f2bf(Ev.x), (short)f2bf(Ev.y),
                              (short)f2bf(Ev.z), (short)f2bf(Ev.w)};
                short4v np_ = {(short)f2bf(nv.x), (short)f2bf(nv.y),
                               (short)f2bf(nv.z), (short)f2bf(nv.w)};
                *(short4v*)&Ml[bl * MSTRIDE + i0] = ep;
                *(short4v*)&Ml[bl * MSTRIDE + 512 + i0] = np_;
            } else if (i0 < FEATN) {      // i0 == 500
                const float Ev = E[base + i0];
                const float nv = nu[base + i0];
                const float iv = 1.0f / nv;
                s1 += iv;
                s2 = fmaf(Ev, iv * iv, s2);
                Ml[bl * MSTRIDE + i0] = f2bf(Ev);
                Ml[bl * MSTRIDE + 512 + i0] = f2bf(nv);
            }
        }
        if (t16 < 11) {                   // zero pads 501..511, 1013..1023
            Ml[bl * MSTRIDE + FEATN + t16] = 0;
            Ml[bl * MSTRIDE + 512 + FEATN + t16] = 0;
        }
        #pragma unroll
        for (int o = 1; o < 16; o <<= 1) {
            s1 += __shfl_xor(s1, o);
            s2 += __shfl_xor(s2, o);
        }
        if (t16 == 0) {
            const float np = (float)FEATN / s1;
            nups[bl] = np;
            Eps[bl] = (s2 / (float)FEATN) * np * np;
        }
    }
    __syncthreads();

    // ---- K loop: no barriers, W from L2, B from static LDS ----
    const int r15 = lane & 15, kg = lane >> 4;
    const ushort* wp0 = Wt + (size_t)(wv * 32 + r15) * KPAD + kg * 8;
    const ushort* wp1 = wp0 + 16 * KPAD;
    const int boff = r15 * MSTRIDE + kg * 8;

    f32x4 acc0 = {0.f, 0.f, 0.f, 0.f}, acc1 = acc0;
    #pragma unroll 4
    for (int s = 0; s < 32; ++s) {
        const int kb = s * 32;
        const short8 a0 = *(const short8*)(wp0 + kb);
        const short8 a1 = *(const short8*)(wp1 + kb);
        const short8 b = *(const short8*)&Ml[boff + kb];
        acc0 = __builtin_amdgcn_mfma_f32_16x16x32_bf16(a0, b, acc0, 0, 0, 0);
        acc1 = __builtin_amdgcn_mfma_f32_16x16x32_bf16(a1, b, acc1, 0, 0, 0);
    }

    // ---- bias + activation -> hid ----
    #pragma unroll
    for (int t = 0; t < 2; ++t) {
        #pragma unroll
        for (int r = 0; r < 4; ++r) {
            const int h = wv * 32 + t * 16 + kg * 4 + r;
            const float bias = (h < 64) ? Bb1[h] : bb1[h - 64];
            float v = (t ? acc1[r] : acc0[r]) + bias;
            v = (h < 64) ? fmaxf(v, 0.f) : softplus_f(v);
            hid[h][r15] = v;
        }
    }
    __syncthreads();

    // ---- layer 2 + coefficient write ----
    if (tid < 128) {
        const int bl = tid >> 3, k = tid & 7;
        float dB = 0.f, db = 0.f;
        #pragma unroll 8
        for (int h = 0; h < 64; ++h) {
            dB = fmaf(hid[h][bl], Bw2[h * 8 + k], dB);
            db = fmaf(hid[64 + h][bl], bw2[h * 8 + k], db);
        }
        const float Bm = dB + Bb2[k];
        const float be = softplus_f(db + bb2[k]);
        float Bs = Bm;
        Bs += __shfl_xor(Bs, 1);
        Bs += __shfl_xor(Bs, 2);
        Bs += __shfl_xor(Bs, 4);
        float* cb = xi + (size_t)(bb0 + bl) * 4096;
        cb[k] = 1.f - DTC * be * (Bm + Bs);
        cb[8 + k] = DTC * be * Bm;
        cb[16 + k] = Bm;
        if (k == 0) { cb[24] = Bs * Eps[bl]; cb[25] = nups[bl]; }
    }
}

// ---------------- time loop: LDS-staged inputs, store-only main loop -------
// grid 2048 x 256: one wave per batch. lane = j*8+k.
// Carry update via shuffle broadcast of lane (j=7)'s xi: x(t0+8) = a*x(t0+7)+c*u7.
__global__ __launch_bounds__(256) void time_kernel(
    const float* __restrict__ e, const float* __restrict__ ed,
    const float* coef, float* stress, float* xi_out) {
    __shared__ float els[4][512];
    __shared__ float pls[4][512];
    const int wv = threadIdx.x >> 6;
    const int wid = (blockIdx.x << 2) + wv;
    const int lane = threadIdx.x & 63;
    const int j = lane >> 3, k = lane & 7;

    const float* eb = e + (size_t)wid * NT;
    const float* edb = ed + (size_t)wid * NT;
    // stage this wave's entire input (wave-local: no barrier needed)
    gl_lds16(eb + lane * 4, &els[wv][0]);
    gl_lds16(eb + 256 + lane * 4, &els[wv][256]);
    gl_lds16(edb + lane * 4, &pls[wv][0]);
    gl_lds16(edb + 256 + lane * 4, &pls[wv][256]);

    const float* cb = coef + (size_t)wid * 4096;
    const float a = cb[k];
    const float c = cb[8 + k];
    const float Bm = cb[16 + k];
    const float sE = cb[24];
    const float nup = cb[25];
    // coef loads + LDS staging must land before LDS reads / aliased stores
    asm volatile("s_waitcnt vmcnt(0)" ::: "memory");

    // per-lane window constants: xi(t0+j) = a^j xi(t0) + sum_{i<j} a^(j-1-i) c u_i
    const float a2 = a * a, a4 = a2 * a2;
    float A = 1.f;                           // a^j
    if (j & 1) A *= a;
    if (j & 2) A *= a2;
    if (j & 4) A *= a4;
    float pw[8];                             // pw[i] = (i<j) ? a^(j-1-i)*c : 0
    {
        float run = c;
        #pragma unroll
        for (int i = 7; i >= 0; --i) {
            const bool on = (i < j);
            pw[i] = on ? run : 0.f;
            run = on ? run * a : run;
        }
    }

    float* xb = xi_out + (size_t)wid * (NT * 8);
    float* sb = stress + (size_t)wid * NT;
    const float* el = &els[wv][0];
    const float* pl = &pls[wv][0];

    // register-pipelined window reads from LDS
    float4 q0 = *(const float4*)(el);
    float4 q1 = *(const float4*)(el + 4);
    float uj = el[j];
    float pj = pl[j];

    float xs = 0.f;
    #pragma unroll 2
    for (int t0 = 0; t0 < NT; t0 += 8) {
        const float u0 = q0.x, u1 = q0.y, u2 = q0.z, u3 = q0.w;
        const float u4 = q1.x, u5 = q1.y, u6 = q1.z, u7 = q1.w;
        const float cuj = uj, cpj = pj;
        if (t0 + 8 < NT) {                   // prefetch next window (LDS)
            q0 = *(const float4*)(el + t0 + 8);
            q1 = *(const float4*)(el + t0 + 12);
            uj = el[t0 + 8 + j];
            pj = pl[t0 + 8 + j];
        }
        float xi_j = A * xs;
        xi_j = fmaf(pw[0], u0, xi_j);
        xi_j = fmaf(pw[1], u1, xi_j);
        xi_j = fmaf(pw[2], u2, xi_j);
        xi_j = fmaf(pw[3], u3, xi_j);
        xi_j = fmaf(pw[4], u4, xi_j);
        xi_j = fmaf(pw[5], u5, xi_j);
        xi_j = fmaf(pw[6], u6, xi_j);
        xi_j = fmaf(pw[7], u7, xi_j);
        xb[t0 * 8 + lane] = xi_j;            // coalesced 256B/wave
        float r = Bm * (cuj - xi_j);
        r = dpp_add(r, 0xB1);                // + lane^1
        r = dpp_add(r, 0x4E);                // + lane^2
        r = dpp_add(r, 0x141);               // + other quad (within 8)
        if (k == 0) sb[t0 + j] = fmaf(sE, cuj, fmaf(nup, cpj, r));
        // carry: x(t0+8) = a * x(t0+7) + c*u7 ; x(t0+7) sits in lane 56+k
        xs = fmaf(a, __shfl(xi_j, 56 + k), c * u7);
    }
}

extern "C" void kernel_launch(void* const* d_in, const int* in_sizes, int n_in,
                              void* d_out, int out_size, void* d_ws, size_t ws_size,
                              hipStream_t stream) {
    const float* e   = (const float*)d_in[0];
    const float* ed  = (const float*)d_in[1];
    const float* E   = (const float*)d_in[2];
    const float* nu  = (const float*)d_in[3];
    const float* Bw1 = (const float*)d_in[4];
    const float* Bb1 = (const float*)d_in[5];
    const float* Bw2 = (const float*)d_in[6];
    const float* Bb2 = (const float*)d_in[7];
    const float* bw1 = (const float*)d_in[8];
    const float* bb1 = (const float*)d_in[9];
    const float* bw2 = (const float*)d_in[10];
    const float* bb2 = (const float*)d_in[11];

    float* out = (float*)d_out;
    float* stress = out;                        // [B*T] floats
    float* xi = out + (size_t)NB * NT;          // [B*T*8] floats
    ushort* Wt = (ushort*)out;                  // 256 KB stash in stress region

    wtrans_kernel<<<128, 256, 0, stream>>>(Bw1, bw1, Wt);
    enc_kernel<<<512, 256, 0, stream>>>(E, nu, Wt, Bb1, bb1,
                                        Bw2, Bb2, bw2, bb2, xi);
    time_kernel<<<2048, 256, 0, stream>>>(e, ed, xi, stress, xi);
}